// Round 1
// baseline (365.035 us; speedup 1.0000x reference)
//
#include <hip/hip_runtime.h>
#include <hip/hip_bf16.h>

#define BB 8
#define CC 512
#define NN 2048
#define DD 64

typedef __attribute__((ext_vector_type(8))) short bf16x8;
typedef __attribute__((ext_vector_type(4))) float f32x4;

static __device__ __forceinline__ short f2b(float f) {
    union { __hip_bfloat16 h; short s; } u;
    u.h = __float2bfloat16(f);
    return u.s;
}

// ---------------- Kernel 1: projections f = Wq x, g = Wk x, h = Wv x ----------------
// out rows r: rb==0 -> f (store transposed fT[n][d]), rb==1 -> g (gT[n][d]),
// rb>=2 -> h rows (rb-2)*64.. (store h[c][n]).
__global__ __launch_bounds__(256) void proj_kernel(
    const float* __restrict__ x, const float* __restrict__ Wq,
    const float* __restrict__ Wk, const float* __restrict__ Wv,
    short* __restrict__ fT, short* __restrict__ gT, short* __restrict__ h)
{
    const int rb = blockIdx.x;   // 0..9
    const int nb = blockIdx.y;   // 0..15
    const int b  = blockIdx.z;   // 0..7
    const int t  = threadIdx.x;
    const int w  = t >> 6;
    const int l  = t & 63;
    const int lo = l & 15, hi = l >> 4;

    const float* Wp;
    int mode, c_base = 0;
    if (rb == 0)      { Wp = Wq; mode = 0; }
    else if (rb == 1) { Wp = Wk; mode = 1; }
    else              { Wp = Wv + (size_t)(rb - 2) * 64 * CC; mode = 2; c_base = (rb - 2) * 64; }

    const int n0 = nb * 128 + w * 32;
    const float* xb = x + (size_t)b * CC * NN;

    f32x4 acc[4][2];
    #pragma unroll
    for (int i = 0; i < 4; i++)
        #pragma unroll
        for (int j = 0; j < 2; j++) acc[i][j] = (f32x4){0.f, 0.f, 0.f, 0.f};

    for (int k0 = 0; k0 < CC; k0 += 32) {
        // A-fragments: W rows (16 per rf), k contiguous
        bf16x8 a[4];
        #pragma unroll
        for (int rf = 0; rf < 4; rf++) {
            const float* ap = Wp + (size_t)(16 * rf + lo) * CC + k0 + 8 * hi;
            float4 v0 = *reinterpret_cast<const float4*>(ap);
            float4 v1 = *reinterpret_cast<const float4*>(ap + 4);
            bf16x8 av;
            av[0] = f2b(v0.x); av[1] = f2b(v0.y); av[2] = f2b(v0.z); av[3] = f2b(v0.w);
            av[4] = f2b(v1.x); av[5] = f2b(v1.y); av[6] = f2b(v1.z); av[7] = f2b(v1.w);
            a[rf] = av;
        }
        // B-fragments: B[k][n] = x[k][n]; lane holds k = k0+8*hi+j, col n
        bf16x8 bv[2];
        #pragma unroll
        for (int nf = 0; nf < 2; nf++) {
            bf16x8 t8;
            #pragma unroll
            for (int j = 0; j < 8; j++)
                t8[j] = f2b(xb[(size_t)(k0 + 8 * hi + j) * NN + (n0 + 16 * nf + lo)]);
            bv[nf] = t8;
        }
        #pragma unroll
        for (int rf = 0; rf < 4; rf++)
            #pragma unroll
            for (int nf = 0; nf < 2; nf++)
                acc[rf][nf] = __builtin_amdgcn_mfma_f32_16x16x32_bf16(a[rf], bv[nf], acc[rf][nf], 0, 0, 0);
    }

    #pragma unroll
    for (int rf = 0; rf < 4; rf++)
        #pragma unroll
        for (int nf = 0; nf < 2; nf++)
            #pragma unroll
            for (int j = 0; j < 4; j++) {
                int r_loc = 16 * rf + 4 * hi + j;       // D row = (lane>>4)*4 + reg
                int n     = n0 + 16 * nf + lo;           // D col = lane&15
                short v = f2b(acc[rf][nf][j]);
                if (mode == 0)      fT[(size_t)b * NN * DD + (size_t)n * DD + r_loc] = v;
                else if (mode == 1) gT[(size_t)b * NN * DD + (size_t)n * DD + r_loc] = v;
                else                h[(size_t)b * CC * NN + (size_t)(c_base + r_loc) * NN + n] = v;
            }
}

// ---------------- Kernel 2: masked column-softmax attention + residual ----------------
// Block: (b, m-block of 64 columns). Pass A: column max/sum. Pass B: beta tile + PV.
__global__ __launch_bounds__(256, 1) void attn_kernel(
    const short* __restrict__ fT, const short* __restrict__ gT,
    const short* __restrict__ h,  const float* __restrict__ x,
    const float* __restrict__ mask, const float* __restrict__ gamma,
    float* __restrict__ out)
{
    const int mb = blockIdx.x;  // 0..31
    const int b  = blockIdx.y;  // 0..7
    const int t  = threadIdx.x;
    const int w  = t >> 6, l = t & 63, lo = l & 15, hi = l >> 4;
    const int m0 = mb * 64;

    __shared__ __align__(16) short gTs[64][72];
    __shared__ __align__(16) short fTs[64][72];
    __shared__ __align__(16) short betaTs[64][72];
    __shared__ float masks[64];

    // stage g^T m-block once (rows = m_local, cols = d)
    #pragma unroll
    for (int rr = 0; rr < 2; rr++) {
        int row = rr * 32 + (t >> 3), ch = t & 7;
        *reinterpret_cast<int4*>(&gTs[row][ch * 8]) =
            *reinterpret_cast<const int4*>(&gT[((size_t)b * NN + m0 + row) * DD + ch * 8]);
    }
    __syncthreads();

    // query fragments (constant over n loop): B[k=d][col=m]: gTs[16w+lo][kk*32+8*hi..]
    bf16x8 bq[2];
    #pragma unroll
    for (int kk = 0; kk < 2; kk++)
        bq[kk] = *reinterpret_cast<const bf16x8*>(&gTs[16 * w + lo][kk * 32 + 8 * hi]);

    // ---- Pass A: per-column max and masked-exp sum over all n ----
    float m_run = -1e30f, s_run = 0.f;
    for (int nbk = 0; nbk < 32; nbk++) {
        #pragma unroll
        for (int rr = 0; rr < 2; rr++) {
            int row = rr * 32 + (t >> 3), ch = t & 7;
            *reinterpret_cast<int4*>(&fTs[row][ch * 8]) =
                *reinterpret_cast<const int4*>(&fT[((size_t)b * NN + nbk * 64 + row) * DD + ch * 8]);
        }
        if (t < 64) masks[t] = mask[(size_t)b * NN + nbk * 64 + t];
        __syncthreads();

        f32x4 s[4];
        #pragma unroll
        for (int rf = 0; rf < 4; rf++) {
            f32x4 a4 = (f32x4){0.f, 0.f, 0.f, 0.f};
            #pragma unroll
            for (int kk = 0; kk < 2; kk++) {
                bf16x8 af = *reinterpret_cast<const bf16x8*>(&fTs[16 * rf + lo][kk * 32 + 8 * hi]);
                a4 = __builtin_amdgcn_mfma_f32_16x16x32_bf16(af, bq[kk], a4, 0, 0, 0);
            }
            s[rf] = a4;
        }
        float mx = -1e30f;
        #pragma unroll
        for (int rf = 0; rf < 4; rf++)
            #pragma unroll
            for (int j = 0; j < 4; j++) mx = fmaxf(mx, s[rf][j]);
        mx = fmaxf(mx, __shfl_xor(mx, 16));
        mx = fmaxf(mx, __shfl_xor(mx, 32));
        float m_new = fmaxf(m_run, mx);
        float p = 0.f;
        #pragma unroll
        for (int rf = 0; rf < 4; rf++)
            #pragma unroll
            for (int j = 0; j < 4; j++)
                p += masks[16 * rf + 4 * hi + j] * __expf(s[rf][j] - m_new);
        p += __shfl_xor(p, 16);
        p += __shfl_xor(p, 32);
        s_run = s_run * __expf(m_run - m_new) + p;
        m_run = m_new;
        __syncthreads();
    }
    const float inv_s = 1.0f / (s_run + 1e-20f);

    // ---- Pass B: recompute scores -> beta tile -> PV accumulate ----
    f32x4 o[8][4];
    #pragma unroll
    for (int ci = 0; ci < 8; ci++)
        #pragma unroll
        for (int mi = 0; mi < 4; mi++) o[ci][mi] = (f32x4){0.f, 0.f, 0.f, 0.f};

    const short* hb = h + (size_t)b * CC * NN;
    for (int nbk = 0; nbk < 32; nbk++) {
        #pragma unroll
        for (int rr = 0; rr < 2; rr++) {
            int row = rr * 32 + (t >> 3), ch = t & 7;
            *reinterpret_cast<int4*>(&fTs[row][ch * 8]) =
                *reinterpret_cast<const int4*>(&fT[((size_t)b * NN + nbk * 64 + row) * DD + ch * 8]);
        }
        if (t < 64) masks[t] = mask[(size_t)b * NN + nbk * 64 + t];
        __syncthreads();

        f32x4 s[4];
        #pragma unroll
        for (int rf = 0; rf < 4; rf++) {
            f32x4 a4 = (f32x4){0.f, 0.f, 0.f, 0.f};
            #pragma unroll
            for (int kk = 0; kk < 2; kk++) {
                bf16x8 af = *reinterpret_cast<const bf16x8*>(&fTs[16 * rf + lo][kk * 32 + 8 * hi]);
                a4 = __builtin_amdgcn_mfma_f32_16x16x32_bf16(af, bq[kk], a4, 0, 0, 0);
            }
            s[rf] = a4;
        }
        // beta^T[m_local][n_local], bf16
        #pragma unroll
        for (int rf = 0; rf < 4; rf++)
            #pragma unroll
            for (int j = 0; j < 4; j++) {
                int n_loc = 16 * rf + 4 * hi + j;
                float v = masks[n_loc] * __expf(s[rf][j] - m_run) * inv_s;
                betaTs[16 * w + lo][n_loc] = f2b(v);
            }
        __syncthreads();

        // PV: wave owns c-slice [128w, 128w+128); A = h rows, B = beta
        #pragma unroll
        for (int kk = 0; kk < 2; kk++) {
            bf16x8 bb[4];
            #pragma unroll
            for (int mi = 0; mi < 4; mi++)
                bb[mi] = *reinterpret_cast<const bf16x8*>(&betaTs[16 * mi + lo][kk * 32 + 8 * hi]);
            #pragma unroll
            for (int ci = 0; ci < 8; ci++) {
                const short* hp = hb + (size_t)(128 * w + 16 * ci + lo) * NN + nbk * 64 + kk * 32 + 8 * hi;
                bf16x8 af = *reinterpret_cast<const bf16x8*>(hp);
                #pragma unroll
                for (int mi = 0; mi < 4; mi++)
                    o[ci][mi] = __builtin_amdgcn_mfma_f32_16x16x32_bf16(af, bb[mi], o[ci][mi], 0, 0, 0);
            }
        }
        // next iteration's beta writes are fenced by the post-stage __syncthreads
    }

    // epilogue: out = gamma * o + x
    const float gm = gamma[0];
    const float* xb = x + (size_t)b * CC * NN;
    float* ob = out + (size_t)b * CC * NN;
    #pragma unroll
    for (int ci = 0; ci < 8; ci++)
        #pragma unroll
        for (int mi = 0; mi < 4; mi++)
            #pragma unroll
            for (int j = 0; j < 4; j++) {
                int c = 128 * w + 16 * ci + 4 * hi + j;
                int m = m0 + 16 * mi + lo;
                size_t idx = (size_t)c * NN + m;
                ob[idx] = gm * o[ci][mi][j] + xb[idx];
            }
}

extern "C" void kernel_launch(void* const* d_in, const int* in_sizes, int n_in,
                              void* d_out, int out_size, void* d_ws, size_t ws_size,
                              hipStream_t stream) {
    (void)in_sizes; (void)n_in; (void)out_size; (void)ws_size;
    const float* x     = (const float*)d_in[0];
    const float* mask  = (const float*)d_in[1];
    const float* Wq    = (const float*)d_in[2];
    const float* Wk    = (const float*)d_in[3];
    const float* Wv    = (const float*)d_in[4];
    const float* gamma = (const float*)d_in[5];
    float* out = (float*)d_out;

    char* ws = (char*)d_ws;
    short* fT = (short*)ws;                                          // 8*2048*64 bf16 = 2 MB
    short* gT = (short*)(ws + (size_t)BB * NN * DD * 2);             // 2 MB
    short* h  = (short*)(ws + (size_t)2 * BB * NN * DD * 2);         // 8*512*2048 bf16 = 16 MB

    dim3 g1(10, 16, BB);
    proj_kernel<<<g1, 256, 0, stream>>>(x, Wq, Wk, Wv, fT, gT, h);

    dim3 g2(32, BB);
    attn_kernel<<<g2, 256, 0, stream>>>(fT, gT, h, x, mask, gamma, out);
}

// Round 2
// 226.618 us; speedup vs baseline: 1.6108x; 1.6108x over previous
//
#include <hip/hip_runtime.h>
#include <hip/hip_bf16.h>

#define BB 8
#define CC 512
#define NN 2048
#define DD 64

typedef __attribute__((ext_vector_type(8))) _Float16 f16x8;
typedef __attribute__((ext_vector_type(4))) _Float16 f16x4;
typedef __attribute__((ext_vector_type(4))) float f32x4;

// ---------------- Kernel 1: projections f = Wq x, g = Wk x, h = Wv x ----------------
// Grid (32 nb, 8 b), 512 threads. Each block: all 640 out rows x 64-col n-tile.
// x staged once to LDS (transposed, fp16). Wave w owns rows 80w..80w+79 (5 rf).
__global__ __launch_bounds__(512, 2) void proj_kernel(
    const float* __restrict__ x, const float* __restrict__ Wq,
    const float* __restrict__ Wk, const float* __restrict__ Wv,
    _Float16* __restrict__ fT, _Float16* __restrict__ gT, _Float16* __restrict__ h)
{
    const int nb = blockIdx.x;   // 0..31
    const int b  = blockIdx.y;   // 0..7
    const int n0 = nb * 64;
    const int t  = threadIdx.x;
    const int w  = t >> 6;
    const int l  = t & 63;
    const int lo = l & 15, hi = l >> 4;
    const float* xb = x + (size_t)b * CC * NN;

    __shared__ _Float16 xs[64][72];   // [n_local][k_local], pad 72

    f32x4 acc[5][4];
    #pragma unroll
    for (int i = 0; i < 5; i++)
        #pragma unroll
        for (int j = 0; j < 4; j++) acc[i][j] = (f32x4){0.f, 0.f, 0.f, 0.f};

    for (int k0 = 0; k0 < CC; k0 += 64) {
        if (t < 256) {
            int kb = t >> 4, nq = t & 15;   // kb: 16 k-quads, nq: 16 n-quads
            const float* src = xb + (size_t)(k0 + 4 * kb) * NN + n0 + 4 * nq;
            float4 v0 = *reinterpret_cast<const float4*>(src);
            float4 v1 = *reinterpret_cast<const float4*>(src + NN);
            float4 v2 = *reinterpret_cast<const float4*>(src + 2 * NN);
            float4 v3 = *reinterpret_cast<const float4*>(src + 3 * NN);
            f16x4 t0 = {(_Float16)v0.x, (_Float16)v1.x, (_Float16)v2.x, (_Float16)v3.x};
            f16x4 t1 = {(_Float16)v0.y, (_Float16)v1.y, (_Float16)v2.y, (_Float16)v3.y};
            f16x4 t2 = {(_Float16)v0.z, (_Float16)v1.z, (_Float16)v2.z, (_Float16)v3.z};
            f16x4 t3 = {(_Float16)v0.w, (_Float16)v1.w, (_Float16)v2.w, (_Float16)v3.w};
            *reinterpret_cast<f16x4*>(&xs[4 * nq + 0][4 * kb]) = t0;
            *reinterpret_cast<f16x4*>(&xs[4 * nq + 1][4 * kb]) = t1;
            *reinterpret_cast<f16x4*>(&xs[4 * nq + 2][4 * kb]) = t2;
            *reinterpret_cast<f16x4*>(&xs[4 * nq + 3][4 * kb]) = t3;
        }
        __syncthreads();

        #pragma unroll
        for (int kk = 0; kk < 2; kk++) {
            f16x8 bv[4];
            #pragma unroll
            for (int nf = 0; nf < 4; nf++)
                bv[nf] = *reinterpret_cast<const f16x8*>(&xs[16 * nf + lo][32 * kk + 8 * hi]);
            #pragma unroll
            for (int rf = 0; rf < 5; rf++) {
                int Rb = 80 * w + 16 * rf;
                const float* prow; int Rr;
                if (Rb < 64)       { prow = Wq; Rr = Rb; }
                else if (Rb < 128) { prow = Wk; Rr = Rb - 64; }
                else               { prow = Wv; Rr = Rb - 128; }
                const float* ap = prow + (size_t)(Rr + lo) * CC + k0 + 32 * kk + 8 * hi;
                float4 a0 = *reinterpret_cast<const float4*>(ap);
                float4 a1 = *reinterpret_cast<const float4*>(ap + 4);
                f16x8 af = {(_Float16)a0.x, (_Float16)a0.y, (_Float16)a0.z, (_Float16)a0.w,
                            (_Float16)a1.x, (_Float16)a1.y, (_Float16)a1.z, (_Float16)a1.w};
                #pragma unroll
                for (int nf = 0; nf < 4; nf++)
                    acc[rf][nf] = __builtin_amdgcn_mfma_f32_16x16x32_f16(af, bv[nf], acc[rf][nf], 0, 0, 0);
            }
        }
        __syncthreads();
    }

    // Epilogue: D row = 4*hi + j within 16-row fragment; D col = lo.
    #pragma unroll
    for (int rf = 0; rf < 5; rf++) {
        int Rb = 80 * w + 16 * rf;   // wave-uniform, no 64/128 straddle (mult of 16)
        #pragma unroll
        for (int nf = 0; nf < 4; nf++) {
            int n = n0 + 16 * nf + lo;
            if (Rb < 128) {
                f16x4 v = {(_Float16)acc[rf][nf][0], (_Float16)acc[rf][nf][1],
                           (_Float16)acc[rf][nf][2], (_Float16)acc[rf][nf][3]};
                if (Rb < 64)
                    *reinterpret_cast<f16x4*>(&fT[((size_t)b * NN + n) * DD + Rb + 4 * hi]) = v;
                else
                    *reinterpret_cast<f16x4*>(&gT[((size_t)b * NN + n) * DD + (Rb - 64) + 4 * hi]) = v;
            } else {
                #pragma unroll
                for (int j = 0; j < 4; j++)
                    h[(size_t)b * CC * NN + (size_t)(Rb - 128 + 4 * hi + j) * NN + n] =
                        (_Float16)acc[rf][nf][j];
            }
        }
    }
}

// ---------------- Kernel 2: one-pass masked column-softmax attention + residual ------
// 512 threads (8 waves). Wave-group g = w>>2 owns n-blocks 16g..16g+15 (flash-style
// online stats + defer-max). Within group: wave wq = w&3 computes scores for columns
// 16wq+lo and PV for c-slice 128wq. Group partial o combined via LDS at the end.
__global__ __launch_bounds__(512, 2) void attn_kernel(
    const _Float16* __restrict__ fT, const _Float16* __restrict__ gT,
    const _Float16* __restrict__ h,  const float* __restrict__ x,
    const float* __restrict__ mask, const float* __restrict__ gamma,
    float* __restrict__ out)
{
    const int bid = blockIdx.x;
    const int b  = bid & 7;        // XCD-cluster: all blocks of batch b on one XCD
    const int mb = bid >> 3;       // 0..31
    const int m0 = mb * 64;
    const int t  = threadIdx.x;
    const int w  = t >> 6, l = t & 63, lo = l & 15, hi = l >> 4;
    const int g  = w >> 2, wq = w & 3;
    const int t2 = t & 255;        // group-local tid

    __shared__ _Float16 gTs[64][64];          // swizzled
    __shared__ _Float16 fTs[2][64][64];       // swizzled, per group
    __shared__ _Float16 betaTs[2][64][64];    // swizzled, per group
    __shared__ float masks[2][64];
    __shared__ float m_s[2][64], s_s[2][64], ffs[2][64], fac[2][64];
    __shared__ int flagA[2][2];
    __shared__ float obuf[2][128][68];

    // stage g^T m-block once (row = m_local, XOR-swizzled 16B slots)
    {
        int row = t >> 3, sl = t & 7;
        int4 v = *reinterpret_cast<const int4*>(&gT[((size_t)b * NN + m0 + row) * DD + sl * 8]);
        *reinterpret_cast<int4*>(&gTs[row][(sl ^ (row & 7)) * 8]) = v;
    }
    __syncthreads();

    f16x8 bq[2];
    {
        int row = 16 * wq + lo;
        #pragma unroll
        for (int kk = 0; kk < 2; kk++)
            bq[kk] = *reinterpret_cast<const f16x8*>(&gTs[row][((4 * kk + hi) ^ (row & 7)) * 8]);
    }

    f32x4 o[8][4];
    #pragma unroll
    for (int ci = 0; ci < 8; ci++)
        #pragma unroll
        for (int mi = 0; mi < 4; mi++) o[ci][mi] = (f32x4){0.f, 0.f, 0.f, 0.f};

    float m_run = -1e30f, s_run = 0.f;
    const _Float16* hb = h + (size_t)b * CC * NN;

    for (int i = 0; i < 16; i++) {
        const int nbk = 16 * g + i;
        // ---- stage fT n-block (per group) ----
        if (t2 == 0) flagA[g][i & 1] = 0;
        {
            int row = t2 >> 2, sl0 = (t2 & 3) * 2;
            const int4* src = reinterpret_cast<const int4*>(
                &fT[((size_t)b * NN + nbk * 64 + row) * DD]);
            int4 v0 = src[sl0], v1 = src[sl0 + 1];
            *reinterpret_cast<int4*>(&fTs[g][row][(sl0 ^ (row & 7)) * 8]) = v0;
            *reinterpret_cast<int4*>(&fTs[g][row][((sl0 + 1) ^ (row & 7)) * 8]) = v1;
        }
        if (t2 < 64) masks[g][t2] = mask[(size_t)b * NN + nbk * 64 + t2];
        __syncthreads();   // A: fTs/masks ready; betaTs free (prev PV done)

        // ---- scores for this wave's 16 columns ----
        f32x4 s4[4];
        #pragma unroll
        for (int rf = 0; rf < 4; rf++) {
            f32x4 a4 = (f32x4){0.f, 0.f, 0.f, 0.f};
            int row = 16 * rf + lo;
            #pragma unroll
            for (int kk = 0; kk < 2; kk++) {
                f16x8 af = *reinterpret_cast<const f16x8*>(
                    &fTs[g][row][((4 * kk + hi) ^ (row & 7)) * 8]);
                a4 = __builtin_amdgcn_mfma_f32_16x16x32_f16(af, bq[kk], a4, 0, 0, 0);
            }
            s4[rf] = a4;
        }
        float pmax = -1e30f;
        #pragma unroll
        for (int rf = 0; rf < 4; rf++)
            #pragma unroll
            for (int j = 0; j < 4; j++) pmax = fmaxf(pmax, s4[rf][j]);
        pmax = fmaxf(pmax, __shfl_xor(pmax, 16));
        pmax = fmaxf(pmax, __shfl_xor(pmax, 32));

        float r = 1.0f;
        bool need = __any(pmax > m_run + 8.0f);
        if (need) {
            float mn = fmaxf(m_run, pmax);
            r = __expf(m_run - mn);
            m_run = mn;
        }
        float p = 0.f;
        {
            int row = 16 * wq + lo;
            #pragma unroll
            for (int rf = 0; rf < 4; rf++) {
                float e0 = masks[g][16 * rf + 4 * hi + 0] * __expf(s4[rf][0] - m_run);
                float e1 = masks[g][16 * rf + 4 * hi + 1] * __expf(s4[rf][1] - m_run);
                float e2 = masks[g][16 * rf + 4 * hi + 2] * __expf(s4[rf][2] - m_run);
                float e3 = masks[g][16 * rf + 4 * hi + 3] * __expf(s4[rf][3] - m_run);
                p += (e0 + e1) + (e2 + e3);
                f16x4 ev = {(_Float16)e0, (_Float16)e1, (_Float16)e2, (_Float16)e3};
                int col = 16 * rf + 4 * hi;
                int sl  = col >> 3, off = col & 7;
                *reinterpret_cast<f16x4*>(&betaTs[g][row][(sl ^ (row & 7)) * 8 + off]) = ev;
            }
        }
        p += __shfl_xor(p, 16);
        p += __shfl_xor(p, 32);
        s_run = s_run * r + p;
        if (hi == 0) fac[g][16 * wq + lo] = r;
        if (need && l == 0) flagA[g][i & 1] = 1;
        __syncthreads();   // B: betaTs/fac/flag ready

        int fl = flagA[g][i & 1];
        if (fl) {
            #pragma unroll
            for (int mi = 0; mi < 4; mi++) {
                float fr = fac[g][16 * mi + lo];
                #pragma unroll
                for (int ci = 0; ci < 8; ci++) {
                    o[ci][mi][0] *= fr; o[ci][mi][1] *= fr;
                    o[ci][mi][2] *= fr; o[ci][mi][3] *= fr;
                }
            }
        }
        // ---- PV: c-slice 128*wq, h A-frags from global (L2-resident) ----
        #pragma unroll
        for (int kk = 0; kk < 2; kk++) {
            f16x8 bb[4];
            #pragma unroll
            for (int mi = 0; mi < 4; mi++) {
                int row = 16 * mi + lo;
                bb[mi] = *reinterpret_cast<const f16x8*>(
                    &betaTs[g][row][((4 * kk + hi) ^ (row & 7)) * 8]);
            }
            #pragma unroll
            for (int ci = 0; ci < 8; ci++) {
                f16x8 af = *reinterpret_cast<const f16x8*>(
                    &hb[(size_t)(128 * wq + 16 * ci + lo) * NN + nbk * 64 + 32 * kk + 8 * hi]);
                #pragma unroll
                for (int mi = 0; mi < 4; mi++)
                    o[ci][mi] = __builtin_amdgcn_mfma_f32_16x16x32_f16(af, bb[mi], o[ci][mi], 0, 0, 0);
            }
        }
    }

    // ---- combine group stats ----
    if (hi == 0) { m_s[g][16 * wq + lo] = m_run; s_s[g][16 * wq + lo] = s_run; }
    __syncthreads();
    if (t < 128) {
        int gg = t >> 6, m = t & 63;
        float M = fmaxf(m_s[0][m], m_s[1][m]);
        float S = s_s[0][m] * __expf(m_s[0][m] - M) + s_s[1][m] * __expf(m_s[1][m] - M) + 1e-20f;
        ffs[gg][m] = __expf(m_s[gg][m] - M) / S;
    }
    __syncthreads();
    {
        float fsc[4];
        #pragma unroll
        for (int mi = 0; mi < 4; mi++) fsc[mi] = ffs[g][16 * mi + lo];
        #pragma unroll
        for (int ci = 0; ci < 8; ci++)
            #pragma unroll
            for (int mi = 0; mi < 4; mi++) {
                o[ci][mi][0] *= fsc[mi]; o[ci][mi][1] *= fsc[mi];
                o[ci][mi][2] *= fsc[mi]; o[ci][mi][3] *= fsc[mi];
            }
    }

    // ---- combine o across groups + epilogue (two rounds of 256 c-rows) ----
    const float gm = gamma[0];
    const float* xb = x + (size_t)b * CC * NN;
    float* ob = out + (size_t)b * CC * NN;

    #pragma unroll
    for (int round = 0; round < 2; round++) {
        int wqlo = round * 2;
        if (g == 1 && wq >= wqlo && wq < wqlo + 2) {
            int s = wq - wqlo;
            #pragma unroll
            for (int ci = 0; ci < 8; ci++)
                #pragma unroll
                for (int mi = 0; mi < 4; mi++)
                    #pragma unroll
                    for (int j = 0; j < 4; j++)
                        obuf[s][16 * ci + 4 * hi + j][16 * mi + lo] = o[ci][mi][j];
        }
        __syncthreads();
        if (g == 0 && wq >= wqlo && wq < wqlo + 2) {
            int s = wq - wqlo;
            #pragma unroll
            for (int ci = 0; ci < 8; ci++)
                #pragma unroll
                for (int mi = 0; mi < 4; mi++)
                    #pragma unroll
                    for (int j = 0; j < 4; j++)
                        obuf[s][16 * ci + 4 * hi + j][16 * mi + lo] += o[ci][mi][j];
        }
        __syncthreads();
        int cbase = round * 256;
        #pragma unroll
        for (int rr = 0; rr < 8; rr++) {
            int c_loc = 32 * w + 4 * rr + (l >> 4);   // 0..255
            int m_loc = 4 * (l & 15);
            float4 v = *reinterpret_cast<const float4*>(&obuf[c_loc >> 7][c_loc & 127][m_loc]);
            size_t idx = (size_t)(cbase + c_loc) * NN + m0 + m_loc;
            float4 xv = *reinterpret_cast<const float4*>(xb + idx);
            float4 res;
            res.x = gm * v.x + xv.x; res.y = gm * v.y + xv.y;
            res.z = gm * v.z + xv.z; res.w = gm * v.w + xv.w;
            *reinterpret_cast<float4*>(ob + idx) = res;
        }
        __syncthreads();
    }
}

extern "C" void kernel_launch(void* const* d_in, const int* in_sizes, int n_in,
                              void* d_out, int out_size, void* d_ws, size_t ws_size,
                              hipStream_t stream) {
    (void)in_sizes; (void)n_in; (void)out_size; (void)ws_size;
    const float* x     = (const float*)d_in[0];
    const float* mask  = (const float*)d_in[1];
    const float* Wq    = (const float*)d_in[2];
    const float* Wk    = (const float*)d_in[3];
    const float* Wv    = (const float*)d_in[4];
    const float* gamma = (const float*)d_in[5];
    float* out = (float*)d_out;

    char* ws = (char*)d_ws;
    _Float16* fT = (_Float16*)ws;                                    // 2 MB
    _Float16* gT = (_Float16*)(ws + (size_t)BB * NN * DD * 2);       // 2 MB
    _Float16* h  = (_Float16*)(ws + (size_t)2 * BB * NN * DD * 2);   // 16 MB

    dim3 g1(32, BB);
    proj_kernel<<<g1, 512, 0, stream>>>(x, Wq, Wk, Wv, fT, gT, h);

    attn_kernel<<<256, 512, 0, stream>>>(fT, gT, h, x, mask, gamma, out);
}

// Round 3
// 206.196 us; speedup vs baseline: 1.7703x; 1.0990x over previous
//
#include <hip/hip_runtime.h>
#include <hip/hip_bf16.h>

#define BB 8
#define CC 512
#define NN 2048
#define DD 64

typedef __attribute__((ext_vector_type(8))) _Float16 f16x8;
typedef __attribute__((ext_vector_type(4))) _Float16 f16x4;
typedef __attribute__((ext_vector_type(4))) float f32x4;

// ---- workspace layout (bytes) ----
#define WS_XT  0u                 // xT fp16 [b][n][c]   16 MB
#define WS_WF  16777216u          // Wf fp16 [640][512]  0.65 MB
#define WS_FT  17432576u          // fT fp16 [b][n][64]  2 MB
#define WS_GT  19529728u          // gT fp16 [b][m][64]  2 MB
#define WS_H   21626880u          // h' fp16 [b][c][n]   16 MB (mask folded in)
#define WS_M   38404096u          // M  f32  [b][m]
#define WS_IS  38469632u          // 1/S f32 [b][m]

// ---- dynamic LDS layout for attn2 (bytes) ----
#define HS0 0
#define HS1 65536
#define FS0 131072
#define FS1 139264
#define BTA 147456
#define LDS2B 155648

static __device__ __forceinline__ void gload_lds16(const void* g, void* l) {
    __builtin_amdgcn_global_load_lds(
        (const __attribute__((address_space(1))) void*)g,
        (__attribute__((address_space(3))) void*)l, 16, 0, 0);
}

static __device__ __forceinline__ void hard_barrier() {
    __builtin_amdgcn_sched_barrier(0);
    __builtin_amdgcn_s_barrier();
    __builtin_amdgcn_sched_barrier(0);
}

// =================== Kernel 0: x transpose->fp16 + W convert ===================
// bid < 2048: transpose 64x64 tile of x into xT[b][n][c] fp16.
// bid >= 2048: convert W (Wq|Wk|Wv concat, 640x512) to fp16.
__global__ __launch_bounds__(256) void prep_kernel(
    const float* __restrict__ x, const float* __restrict__ Wq,
    const float* __restrict__ Wk, const float* __restrict__ Wv,
    _Float16* __restrict__ xT, _Float16* __restrict__ Wf)
{
    const int bid = blockIdx.x;
    const int t = threadIdx.x;
    if (bid >= 2048) {
        int e = ((bid - 2048) * 256 + t) * 8;
        const float* src;
        if (e < 32768) src = Wq + e;
        else if (e < 65536) src = Wk + (e - 32768);
        else src = Wv + (e - 65536);
        float4 v0 = *reinterpret_cast<const float4*>(src);
        float4 v1 = *reinterpret_cast<const float4*>(src + 4);
        f16x8 o = {(_Float16)v0.x, (_Float16)v0.y, (_Float16)v0.z, (_Float16)v0.w,
                   (_Float16)v1.x, (_Float16)v1.y, (_Float16)v1.z, (_Float16)v1.w};
        *reinterpret_cast<f16x8*>(Wf + e) = o;
        return;
    }
    __shared__ _Float16 xt[64][72];
    const int b = bid >> 8, ct = (bid >> 5) & 7, nt = bid & 31;
    const int cq = t & 15, nq = t >> 4;     // per-wave lanes: cq 0..15, nq 0..3
    const float* xb = x + ((size_t)b * CC + 64 * ct + 4 * cq) * NN + 64 * nt + 4 * nq;
    float4 v0 = *reinterpret_cast<const float4*>(xb);
    float4 v1 = *reinterpret_cast<const float4*>(xb + NN);
    float4 v2 = *reinterpret_cast<const float4*>(xb + 2 * NN);
    float4 v3 = *reinterpret_cast<const float4*>(xb + 3 * NN);
    *reinterpret_cast<f16x4*>(&xt[4 * nq + 0][4 * cq]) =
        (f16x4){(_Float16)v0.x, (_Float16)v1.x, (_Float16)v2.x, (_Float16)v3.x};
    *reinterpret_cast<f16x4*>(&xt[4 * nq + 1][4 * cq]) =
        (f16x4){(_Float16)v0.y, (_Float16)v1.y, (_Float16)v2.y, (_Float16)v3.y};
    *reinterpret_cast<f16x4*>(&xt[4 * nq + 2][4 * cq]) =
        (f16x4){(_Float16)v0.z, (_Float16)v1.z, (_Float16)v2.z, (_Float16)v3.z};
    *reinterpret_cast<f16x4*>(&xt[4 * nq + 3][4 * cq]) =
        (f16x4){(_Float16)v0.w, (_Float16)v1.w, (_Float16)v2.w, (_Float16)v3.w};
    __syncthreads();
    #pragma unroll
    for (int rr = 0; rr < 2; rr++) {
        int nl = (t >> 3) + 32 * rr, c8 = t & 7;
        f16x8 vv = *reinterpret_cast<const f16x8*>(&xt[nl][8 * c8]);
        *reinterpret_cast<f16x8*>(&xT[((size_t)b * NN + 64 * nt + nl) * CC + 64 * ct + 8 * c8]) = vv;
    }
}

// =================== Kernel 1: projections (pure register GEMM) ===================
// grid (32 nb, 8 b), 512 thr. Wave w -> rows 16*(w+8*rf), rf 0..4.
// rf0: w<4 -> fT rows, w>=4 -> gT rows; rf1..4 -> h rows (mask folded).
__global__ __launch_bounds__(512) void proj_kernel(
    const _Float16* __restrict__ xT, const _Float16* __restrict__ Wf,
    const float* __restrict__ mask,
    _Float16* __restrict__ fT, _Float16* __restrict__ gT, _Float16* __restrict__ h)
{
    const int nb = blockIdx.x, b = blockIdx.y;
    const int n0 = nb * 64;
    const int t = threadIdx.x, w = t >> 6, l = t & 63, lo = l & 15, hi = l >> 4;
    const _Float16* xTb = xT + ((size_t)b * NN + n0) * CC;

    f32x4 acc[5][4];
    #pragma unroll
    for (int i = 0; i < 5; i++)
        #pragma unroll
        for (int j = 0; j < 4; j++) acc[i][j] = (f32x4){0.f, 0.f, 0.f, 0.f};

    #pragma unroll 2
    for (int ks = 0; ks < 16; ks++) {
        f16x8 bfr[4];
        #pragma unroll
        for (int nf = 0; nf < 4; nf++)
            bfr[nf] = *reinterpret_cast<const f16x8*>(xTb + (size_t)(16 * nf + lo) * CC + 32 * ks + 8 * hi);
        #pragma unroll
        for (int rf = 0; rf < 5; rf++) {
            f16x8 af = *reinterpret_cast<const f16x8*>(
                Wf + (size_t)(16 * (w + 8 * rf) + lo) * CC + 32 * ks + 8 * hi);
            #pragma unroll
            for (int nf = 0; nf < 4; nf++)
                acc[rf][nf] = __builtin_amdgcn_mfma_f32_16x16x32_f16(af, bfr[nf], acc[rf][nf], 0, 0, 0);
        }
    }

    float mask4[4];
    #pragma unroll
    for (int nf = 0; nf < 4; nf++) mask4[nf] = mask[(size_t)b * NN + n0 + 16 * nf + lo];

    #pragma unroll
    for (int rf = 0; rf < 5; rf++) {
        int Rb = 16 * (w + 8 * rf);
        #pragma unroll
        for (int nf = 0; nf < 4; nf++) {
            int n = n0 + 16 * nf + lo;
            if (Rb < 64) {
                f16x4 v = {(_Float16)acc[rf][nf][0], (_Float16)acc[rf][nf][1],
                           (_Float16)acc[rf][nf][2], (_Float16)acc[rf][nf][3]};
                *reinterpret_cast<f16x4*>(&fT[((size_t)b * NN + n) * DD + Rb + 4 * hi]) = v;
            } else if (Rb < 128) {
                f16x4 v = {(_Float16)acc[rf][nf][0], (_Float16)acc[rf][nf][1],
                           (_Float16)acc[rf][nf][2], (_Float16)acc[rf][nf][3]};
                *reinterpret_cast<f16x4*>(&gT[((size_t)b * NN + n) * DD + (Rb - 64) + 4 * hi]) = v;
            } else {
                int cr = Rb - 128 + 4 * hi;
                #pragma unroll
                for (int j = 0; j < 4; j++)
                    h[((size_t)b * CC + cr + j) * NN + n] = (_Float16)(acc[rf][nf][j] * mask4[nf]);
            }
        }
    }
}

// =================== Kernel 2a: exact column max + masked exp-sum ===================
// grid 256 (bid&7=b for XCD locality), 512 thr. Wave w reduces n-tiles {w,w+8,w+16,w+24}.
__global__ __launch_bounds__(512) void stats_kernel(
    const _Float16* __restrict__ fT, const _Float16* __restrict__ gT,
    const float* __restrict__ mask, float* __restrict__ Mg, float* __restrict__ iSg)
{
    const int bid = blockIdx.x;
    const int b = bid & 7, mb = bid >> 3;
    const int m0 = mb * 64;
    const int t = threadIdx.x, w = t >> 6, l = t & 63, lo = l & 15, hi = l >> 4;

    __shared__ float masks_all[NN];
    __shared__ float sm[8][64], ss[8][64];

    *reinterpret_cast<float4*>(&masks_all[t * 4]) =
        *reinterpret_cast<const float4*>(&mask[(size_t)b * NN + t * 4]);
    __syncthreads();

    const _Float16* gTb = gT + (size_t)b * NN * DD;
    const _Float16* fTb = fT + (size_t)b * NN * DD;

    f16x8 bq[4][2];
    #pragma unroll
    for (int mf = 0; mf < 4; mf++)
        #pragma unroll
        for (int kk = 0; kk < 2; kk++)
            bq[mf][kk] = *reinterpret_cast<const f16x8*>(
                gTb + (size_t)(m0 + 16 * mf + lo) * DD + 32 * kk + 8 * hi);

    float m_run[4] = {-1e30f, -1e30f, -1e30f, -1e30f};
    float s_run[4] = {0.f, 0.f, 0.f, 0.f};

    for (int tl = 0; tl < 4; tl++) {
        const int nbase = (w + 8 * tl) * 64;
        f16x8 afr[4][2];
        #pragma unroll
        for (int rf = 0; rf < 4; rf++)
            #pragma unroll
            for (int kk = 0; kk < 2; kk++)
                afr[rf][kk] = *reinterpret_cast<const f16x8*>(
                    fTb + (size_t)(nbase + 16 * rf + lo) * DD + 32 * kk + 8 * hi);
        f32x4 s[4][4];
        #pragma unroll
        for (int rf = 0; rf < 4; rf++)
            #pragma unroll
            for (int mf = 0; mf < 4; mf++) {
                f32x4 a4 = (f32x4){0.f, 0.f, 0.f, 0.f};
                a4 = __builtin_amdgcn_mfma_f32_16x16x32_f16(afr[rf][0], bq[mf][0], a4, 0, 0, 0);
                a4 = __builtin_amdgcn_mfma_f32_16x16x32_f16(afr[rf][1], bq[mf][1], a4, 0, 0, 0);
                s[rf][mf] = a4;
            }
        #pragma unroll
        for (int mf = 0; mf < 4; mf++) {
            float mx = -1e30f;
            #pragma unroll
            for (int rf = 0; rf < 4; rf++)
                #pragma unroll
                for (int j = 0; j < 4; j++) mx = fmaxf(mx, s[rf][mf][j]);
            float nm = fmaxf(m_run[mf], mx);
            float sum = 0.f;
            #pragma unroll
            for (int rf = 0; rf < 4; rf++)
                #pragma unroll
                for (int j = 0; j < 4; j++)
                    sum += masks_all[nbase + 16 * rf + 4 * hi + j] * __expf(s[rf][mf][j] - nm);
            s_run[mf] = s_run[mf] * __expf(m_run[mf] - nm) + sum;
            m_run[mf] = nm;
        }
    }
    #pragma unroll
    for (int mf = 0; mf < 4; mf++) {
        #pragma unroll
        for (int d = 16; d <= 32; d <<= 1) {
            float om = __shfl_xor(m_run[mf], d);
            float os = __shfl_xor(s_run[mf], d);
            float nm = fmaxf(m_run[mf], om);
            s_run[mf] = s_run[mf] * __expf(m_run[mf] - nm) + os * __expf(om - nm);
            m_run[mf] = nm;
        }
    }
    if (l < 16) {
        #pragma unroll
        for (int mf = 0; mf < 4; mf++) { sm[w][16 * mf + l] = m_run[mf]; ss[w][16 * mf + l] = s_run[mf]; }
    }
    __syncthreads();
    if (t < 64) {
        float M = -1e30f;
        #pragma unroll
        for (int w8 = 0; w8 < 8; w8++) M = fmaxf(M, sm[w8][t]);
        float S = 0.f;
        #pragma unroll
        for (int w8 = 0; w8 < 8; w8++) S += ss[w8][t] * __expf(sm[w8][t] - M);
        Mg[(size_t)b * NN + m0 + t] = M;
        iSg[(size_t)b * NN + m0 + t] = 1.0f / (S + 1e-20f);
    }
}

// =================== Kernel 2b: beta + PV + residual (DMA-pipelined) ===================
// grid 256 (bid&7=b), 512 thr. Waves: wn=w&3 score n-frag, wm=w>>2 score m-half;
// PV: wave owns c-rows 64w..64w+63. h/fT tiles double-buffered via global_load_lds.
__global__ __launch_bounds__(512) void attn2_kernel(
    const _Float16* __restrict__ fT, const _Float16* __restrict__ gT,
    const _Float16* __restrict__ h, const float* __restrict__ x,
    const float* __restrict__ Mg, const float* __restrict__ iSg,
    const float* __restrict__ gamma, float* __restrict__ out)
{
    extern __shared__ __align__(16) char smem[];
    const int bid = blockIdx.x;
    const int b = bid & 7, mb = bid >> 3;
    const int m0 = mb * 64;
    const int t = threadIdx.x, w = t >> 6, l = t & 63, lo = l & 15, hi = l >> 4;
    const int wn = w & 3, wm = w >> 2;
    const int r3 = l >> 3, c3 = l & 7;
    const int sch = c3 ^ r3;   // pre-swizzled source chunk

    const _Float16* hb = h + (size_t)b * CC * NN;
    const _Float16* fTb = fT + (size_t)b * NN * DD;

    f16x8 bq[2][2]; float Mr[2], iSr[2];
    #pragma unroll
    for (int mf = 0; mf < 2; mf++) {
        int m = m0 + 32 * wm + 16 * mf + lo;
        #pragma unroll
        for (int kk = 0; kk < 2; kk++)
            bq[mf][kk] = *reinterpret_cast<const f16x8*>(
                gT + ((size_t)b * NN + m) * DD + 32 * kk + 8 * hi);
        Mr[mf] = Mg[(size_t)b * NN + m];
        iSr[mf] = iSg[(size_t)b * NN + m];
    }

    f32x4 o[4][4];
    #pragma unroll
    for (int ci = 0; ci < 4; ci++)
        #pragma unroll
        for (int mi = 0; mi < 4; mi++) o[ci][mi] = (f32x4){0.f, 0.f, 0.f, 0.f};

    // ---- staging: 8 h-rows-instrs + 1 fT-instr = 9 loads per wave per tile ----
    #define STAGE(ti, bs) do {                                                         \
        int _n0 = (ti) * 64;                                                           \
        char* _hd = smem + ((bs) ? HS1 : HS0) + (64 * w) * 128;                        \
        const _Float16* _hs = hb + (size_t)(64 * w + r3) * NN + _n0 + sch * 8;         \
        _Pragma("unroll")                                                              \
        for (int _r = 0; _r < 8; _r++)                                                 \
            gload_lds16((const void*)(_hs + (size_t)(8 * _r) * NN), (void*)(_hd + _r * 1024)); \
        char* _fd = smem + ((bs) ? FS1 : FS0) + (8 * w) * 128;                         \
        const _Float16* _fs = fTb + (size_t)(_n0 + 8 * w + r3) * DD + sch * 8;         \
        gload_lds16((const void*)_fs, (void*)_fd);                                     \
    } while (0)

    STAGE(0, 0);

    #pragma unroll 1
    for (int i = 0; i < 32; i++) {
        const int cur = i & 1;
        if (i < 31) {
            STAGE(i + 1, cur ^ 1);
            asm volatile("s_waitcnt vmcnt(9)" ::: "memory");
        } else {
            asm volatile("s_waitcnt vmcnt(0)" ::: "memory");
        }
        hard_barrier();   // buf[cur] ready

        // ---- scores: n-frag wn, m-half wm ----
        char* fsb = smem + (cur ? FS1 : FS0);
        const int arow = 16 * wn + lo;
        f16x8 af0 = *reinterpret_cast<const f16x8*>(fsb + arow * 128 + ((hi ^ (lo & 7)) * 16));
        f16x8 af1 = *reinterpret_cast<const f16x8*>(fsb + arow * 128 + (((4 + hi) ^ (lo & 7)) * 16));
        f32x4 s[2];
        #pragma unroll
        for (int mf = 0; mf < 2; mf++) {
            f32x4 a4 = (f32x4){0.f, 0.f, 0.f, 0.f};
            a4 = __builtin_amdgcn_mfma_f32_16x16x32_f16(af0, bq[mf][0], a4, 0, 0, 0);
            a4 = __builtin_amdgcn_mfma_f32_16x16x32_f16(af1, bq[mf][1], a4, 0, 0, 0);
            s[mf] = a4;
        }

        // ---- beta -> LDS (transposed, swizzled) ----
        char* btb = smem + BTA;
        #pragma unroll
        for (int mf = 0; mf < 2; mf++) {
            f16x4 ev;
            #pragma unroll
            for (int j = 0; j < 4; j++)
                ev[j] = (_Float16)(__expf(s[mf][j] - Mr[mf]) * iSr[mf]);
            int m = 32 * wm + 16 * mf + lo;
            int chunk = (2 * wn + (hi >> 1)) ^ (lo & 7);
            *reinterpret_cast<f16x4*>(btb + m * 128 + chunk * 16 + (hi & 1) * 8) = ev;
        }
        asm volatile("s_waitcnt lgkmcnt(0)" ::: "memory");
        hard_barrier();   // betaTs ready

        // ---- PV: c-rows 64w..64w+63 ----
        char* hsb = smem + (cur ? HS1 : HS0);
        #pragma unroll
        for (int kk = 0; kk < 2; kk++) {
            f16x8 bb[4];
            #pragma unroll
            for (int mi = 0; mi < 4; mi++)
                bb[mi] = *reinterpret_cast<const f16x8*>(
                    btb + (16 * mi + lo) * 128 + (((4 * kk + hi) ^ (lo & 7)) * 16));
            #pragma unroll
            for (int ci = 0; ci < 4; ci++) {
                f16x8 ah = *reinterpret_cast<const f16x8*>(
                    hsb + (64 * w + 16 * ci + lo) * 128 + (((4 * kk + hi) ^ (lo & 7)) * 16));
                #pragma unroll
                for (int mi = 0; mi < 4; mi++)
                    o[ci][mi] = __builtin_amdgcn_mfma_f32_16x16x32_f16(ah, bb[mi], o[ci][mi], 0, 0, 0);
            }
        }
        asm volatile("s_waitcnt lgkmcnt(0)" ::: "memory");
        hard_barrier();   // all reads of buf[cur]/betaTs done
    }
    #undef STAGE

    // ---- epilogue: per-wave LDS transpose (reuse dead buffers) + coalesced store ----
    char* ob = smem + w * 17408;   // 64 rows x 68 f32
    #pragma unroll
    for (int ci = 0; ci < 4; ci++)
        #pragma unroll
        for (int mi = 0; mi < 4; mi++)
            #pragma unroll
            for (int j = 0; j < 4; j++)
                *reinterpret_cast<float*>(ob + (16 * ci + 4 * hi + j) * 272 + (16 * mi + lo) * 4) =
                    o[ci][mi][j];

    const float gm = gamma[0];
    const float* xb = x + (size_t)b * CC * NN;
    float* outb = out + (size_t)b * CC * NN;
    #pragma unroll
    for (int rr = 0; rr < 16; rr++) {
        int row = 4 * rr + hi;
        int mq = lo;
        f32x4 v = *reinterpret_cast<const f32x4*>(ob + row * 272 + mq * 16);
        size_t idx = (size_t)(64 * w + row) * NN + m0 + mq * 4;
        float4 xv = *reinterpret_cast<const float4*>(xb + idx);
        float4 res;
        res.x = gm * v[0] + xv.x; res.y = gm * v[1] + xv.y;
        res.z = gm * v[2] + xv.z; res.w = gm * v[3] + xv.w;
        *reinterpret_cast<float4*>(outb + idx) = res;
    }
}

extern "C" void kernel_launch(void* const* d_in, const int* in_sizes, int n_in,
                              void* d_out, int out_size, void* d_ws, size_t ws_size,
                              hipStream_t stream) {
    (void)in_sizes; (void)n_in; (void)out_size; (void)ws_size;
    const float* x     = (const float*)d_in[0];
    const float* mask  = (const float*)d_in[1];
    const float* Wq    = (const float*)d_in[2];
    const float* Wk    = (const float*)d_in[3];
    const float* Wv    = (const float*)d_in[4];
    const float* gamma = (const float*)d_in[5];
    float* out = (float*)d_out;

    char* ws = (char*)d_ws;
    _Float16* xT = (_Float16*)(ws + WS_XT);
    _Float16* Wf = (_Float16*)(ws + WS_WF);
    _Float16* fT = (_Float16*)(ws + WS_FT);
    _Float16* gT = (_Float16*)(ws + WS_GT);
    _Float16* h  = (_Float16*)(ws + WS_H);
    float* Mg  = (float*)(ws + WS_M);
    float* iSg = (float*)(ws + WS_IS);

    prep_kernel<<<2208, 256, 0, stream>>>(x, Wq, Wk, Wv, xT, Wf);
    proj_kernel<<<dim3(32, 8), 512, 0, stream>>>(xT, Wf, mask, fT, gT, h);
    stats_kernel<<<256, 512, 0, stream>>>(fT, gT, mask, Mg, iSg);
    hipFuncSetAttribute((const void*)attn2_kernel,
                        hipFuncAttributeMaxDynamicSharedMemorySize, LDS2B);
    attn2_kernel<<<256, 512, LDS2B, stream>>>(fT, gT, h, x, Mg, iSg, gamma, out);
}

// Round 4
// 188.056 us; speedup vs baseline: 1.9411x; 1.0965x over previous
//
#include <hip/hip_runtime.h>
#include <hip/hip_bf16.h>

#define BB 8
#define CC 512
#define NN 2048
#define DD 64

typedef __attribute__((ext_vector_type(8))) _Float16 f16x8;
typedef __attribute__((ext_vector_type(4))) _Float16 f16x4;
typedef __attribute__((ext_vector_type(4))) float f32x4;

// ---- workspace layout (bytes) ----
#define WS_WF 0u          // Wf  f16 [640][512]      0.65 MB
#define WS_FT 1048576u    // fT  f16 [b][n][64]      2 MB
#define WS_GT 3145728u    // gT  f16 [b][m][64]      2 MB
#define WS_H  5242880u    // h'  f16 [b][c][n]       16 MB (mask folded)
#define WS_M  22020096u   // M partials f32 [2][b][m] 128 KB
#define WS_S  22151168u   // S partials f32 [2][b][m] 128 KB

// ---- attn2 dynamic LDS (bytes) ----
#define HS0 0             // h tile  [2][256][64] f16 (2x32KB)
#define FS0 65536         // fT tile [2][64][64]  f16 (2x8KB)
#define BT0 81920         // beta^T  [2][128][64] f16 (2x16KB)
#define LDS2B 114688

static __device__ __forceinline__ void gload_lds16(const void* g, void* l) {
    __builtin_amdgcn_global_load_lds(
        (const __attribute__((address_space(1))) void*)g,
        (__attribute__((address_space(3))) void*)l, 16, 0, 0);
}

static __device__ __forceinline__ void hard_barrier() {
    __builtin_amdgcn_sched_barrier(0);
    __builtin_amdgcn_s_barrier();
    __builtin_amdgcn_sched_barrier(0);
}

// =================== Kernel 0: W -> fp16 ===================
__global__ __launch_bounds__(256) void wconv_kernel(
    const float* __restrict__ Wq, const float* __restrict__ Wk,
    const float* __restrict__ Wv, _Float16* __restrict__ Wf)
{
    int e = (blockIdx.x * 256 + threadIdx.x) * 8;
    const float* src;
    if (e < 32768) src = Wq + e;
    else if (e < 65536) src = Wk + (e - 32768);
    else src = Wv + (e - 65536);
    float4 v0 = *reinterpret_cast<const float4*>(src);
    float4 v1 = *reinterpret_cast<const float4*>(src + 4);
    f16x8 o = {(_Float16)v0.x, (_Float16)v0.y, (_Float16)v0.z, (_Float16)v0.w,
               (_Float16)v1.x, (_Float16)v1.y, (_Float16)v1.z, (_Float16)v1.w};
    *reinterpret_cast<f16x8*>(Wf + e) = o;
}

// =================== Kernel 1: projections, x transposed in-kernel ===================
// grid (32 nb, 8 b), 512 thr, 2 blocks/CU. xs[n][c] fp16 swizzled (chunk ^= n&7).
__global__ __launch_bounds__(512, 2) void proj_kernel(
    const float* __restrict__ x, const _Float16* __restrict__ Wf,
    const float* __restrict__ mask,
    _Float16* __restrict__ fT, _Float16* __restrict__ gT, _Float16* __restrict__ h)
{
    const int nb = blockIdx.x, b = blockIdx.y;
    const int n0 = nb * 64;
    const int t = threadIdx.x, w = t >> 6, l = t & 63, lo = l & 15, hi = l >> 4;

    __shared__ _Float16 xs[64][512];

    const float* xb = x + (size_t)b * CC * NN + n0;
    {
        const int cq = t >> 4, nq = t & 15;
        #pragma unroll 4
        for (int p = 0; p < 16; p++) {
            int c = 32 * p + cq;
            float4 v = *reinterpret_cast<const float4*>(xb + (size_t)c * NN + 4 * nq);
            int cc = c >> 3, cb = c & 7;
            float vv[4] = {v.x, v.y, v.z, v.w};
            #pragma unroll
            for (int j = 0; j < 4; j++) {
                int n = 4 * nq + j;
                xs[n][(((cc ^ (n & 7)) << 3) | cb)] = (_Float16)vv[j];
            }
        }
    }
    __syncthreads();

    f32x4 acc[5][4];
    #pragma unroll
    for (int i = 0; i < 5; i++)
        #pragma unroll
        for (int j = 0; j < 4; j++) acc[i][j] = (f32x4){0.f, 0.f, 0.f, 0.f};

    #pragma unroll 4
    for (int ks = 0; ks < 16; ks++) {
        f16x8 bfr[4];
        #pragma unroll
        for (int nf = 0; nf < 4; nf++)
            bfr[nf] = *reinterpret_cast<const f16x8*>(
                &xs[16 * nf + lo][((4 * ks + hi) ^ (lo & 7)) << 3]);
        #pragma unroll
        for (int rf = 0; rf < 5; rf++) {
            f16x8 af = *reinterpret_cast<const f16x8*>(
                Wf + (size_t)(16 * (w + 8 * rf) + lo) * CC + 32 * ks + 8 * hi);
            #pragma unroll
            for (int nf = 0; nf < 4; nf++)
                acc[rf][nf] = __builtin_amdgcn_mfma_f32_16x16x32_f16(af, bfr[nf], acc[rf][nf], 0, 0, 0);
        }
    }

    float mask4[4];
    #pragma unroll
    for (int nf = 0; nf < 4; nf++) mask4[nf] = mask[(size_t)b * NN + n0 + 16 * nf + lo];

    #pragma unroll
    for (int rf = 0; rf < 5; rf++) {
        int Rb = 16 * (w + 8 * rf);
        #pragma unroll
        for (int nf = 0; nf < 4; nf++) {
            int n = n0 + 16 * nf + lo;
            if (Rb < 64) {
                f16x4 v = {(_Float16)acc[rf][nf][0], (_Float16)acc[rf][nf][1],
                           (_Float16)acc[rf][nf][2], (_Float16)acc[rf][nf][3]};
                *reinterpret_cast<f16x4*>(&fT[((size_t)b * NN + n) * DD + Rb + 4 * hi]) = v;
            } else if (Rb < 128) {
                f16x4 v = {(_Float16)acc[rf][nf][0], (_Float16)acc[rf][nf][1],
                           (_Float16)acc[rf][nf][2], (_Float16)acc[rf][nf][3]};
                *reinterpret_cast<f16x4*>(&gT[((size_t)b * NN + n) * DD + (Rb - 64) + 4 * hi]) = v;
            } else {
                int cr = Rb - 128 + 4 * hi;
                #pragma unroll
                for (int j = 0; j < 4; j++)
                    h[((size_t)b * CC + cr + j) * NN + n] = (_Float16)(acc[rf][nf][j] * mask4[nf]);
            }
        }
    }
}

// =================== Kernel 2a: split-K column max + masked exp-sum ===================
// grid 512: b=bid&7, mb=(bid>>3)&31, ns=bid>>8 (n-half). Partials (M,S) to ws.
__global__ __launch_bounds__(512, 2) void stats_kernel(
    const _Float16* __restrict__ fT, const _Float16* __restrict__ gT,
    const float* __restrict__ mask, float* __restrict__ Mp, float* __restrict__ Sp)
{
    const int bid = blockIdx.x;
    const int b = bid & 7, mb = (bid >> 3) & 31, ns = bid >> 8;
    const int m0 = mb * 64;
    const int t = threadIdx.x, w = t >> 6, l = t & 63, lo = l & 15, hi = l >> 4;

    __shared__ float masks_l[1024];
    __shared__ float sm[8][64], ss[8][64];

    *reinterpret_cast<float2*>(&masks_l[2 * t]) =
        *reinterpret_cast<const float2*>(&mask[(size_t)b * NN + ns * 1024 + 2 * t]);
    __syncthreads();

    const _Float16* gTb = gT + (size_t)b * NN * DD;
    const _Float16* fTb = fT + ((size_t)b * NN + ns * 1024) * DD;

    f16x8 bq[4][2];
    #pragma unroll
    for (int mf = 0; mf < 4; mf++)
        #pragma unroll
        for (int kk = 0; kk < 2; kk++)
            bq[mf][kk] = *reinterpret_cast<const f16x8*>(
                gTb + (size_t)(m0 + 16 * mf + lo) * DD + 32 * kk + 8 * hi);

    float m_run[4] = {-1e30f, -1e30f, -1e30f, -1e30f};
    float s_run[4] = {0.f, 0.f, 0.f, 0.f};

    #pragma unroll
    for (int tl = 0; tl < 2; tl++) {
        const int nl = (w + 8 * tl) * 64;
        f16x8 afr[4][2];
        #pragma unroll
        for (int rf = 0; rf < 4; rf++)
            #pragma unroll
            for (int kk = 0; kk < 2; kk++)
                afr[rf][kk] = *reinterpret_cast<const f16x8*>(
                    fTb + (size_t)(nl + 16 * rf + lo) * DD + 32 * kk + 8 * hi);
        #pragma unroll
        for (int mf = 0; mf < 4; mf++) {
            f32x4 s4[4];
            #pragma unroll
            for (int rf = 0; rf < 4; rf++) {
                f32x4 a4 = (f32x4){0.f, 0.f, 0.f, 0.f};
                a4 = __builtin_amdgcn_mfma_f32_16x16x32_f16(afr[rf][0], bq[mf][0], a4, 0, 0, 0);
                a4 = __builtin_amdgcn_mfma_f32_16x16x32_f16(afr[rf][1], bq[mf][1], a4, 0, 0, 0);
                s4[rf] = a4;
            }
            float mx = -1e30f;
            #pragma unroll
            for (int rf = 0; rf < 4; rf++)
                #pragma unroll
                for (int j = 0; j < 4; j++) mx = fmaxf(mx, s4[rf][j]);
            float nm = fmaxf(m_run[mf], mx);
            float sum = 0.f;
            #pragma unroll
            for (int rf = 0; rf < 4; rf++)
                #pragma unroll
                for (int j = 0; j < 4; j++)
                    sum += masks_l[nl + 16 * rf + 4 * hi + j] * __expf(s4[rf][j] - nm);
            s_run[mf] = s_run[mf] * __expf(m_run[mf] - nm) + sum;
            m_run[mf] = nm;
        }
    }
    #pragma unroll
    for (int mf = 0; mf < 4; mf++) {
        #pragma unroll
        for (int d = 16; d <= 32; d <<= 1) {
            float om = __shfl_xor(m_run[mf], d);
            float os = __shfl_xor(s_run[mf], d);
            float nm = fmaxf(m_run[mf], om);
            s_run[mf] = s_run[mf] * __expf(m_run[mf] - nm) + os * __expf(om - nm);
            m_run[mf] = nm;
        }
    }
    if (l < 16) {
        #pragma unroll
        for (int mf = 0; mf < 4; mf++) { sm[w][16 * mf + l] = m_run[mf]; ss[w][16 * mf + l] = s_run[mf]; }
    }
    __syncthreads();
    if (t < 64) {
        float M = -1e30f;
        #pragma unroll
        for (int w8 = 0; w8 < 8; w8++) M = fmaxf(M, sm[w8][t]);
        float S = 0.f;
        #pragma unroll
        for (int w8 = 0; w8 < 8; w8++) S += ss[w8][t] * __expf(sm[w8][t] - M);
        Mp[(size_t)(ns * 8 + b) * NN + m0 + t] = M;
        Sp[(size_t)(ns * 8 + b) * NN + m0 + t] = S;
    }
}

// =================== Kernel 2b: beta + PV + residual ===================
// grid 256: b=bid&7, mb2=(bid>>3)&15 (m-tile 128), cs2=bid>>7 (c-half 256).
// 8 waves: scores (n-half w&1, m-group w>>1); PV (c-group w&3, m-half w>>2).
__global__ __launch_bounds__(512, 1) void attn2_kernel(
    const _Float16* __restrict__ fT, const _Float16* __restrict__ gT,
    const _Float16* __restrict__ h, const float* __restrict__ x,
    const float* __restrict__ Mp, const float* __restrict__ Sp,
    const float* __restrict__ gamma, float* __restrict__ out)
{
    extern __shared__ __align__(16) char smem[];
    const int bid = blockIdx.x;
    const int b = bid & 7, mb2 = (bid >> 3) & 15, cs2 = bid >> 7;
    const int m0 = mb2 * 128, cbase = cs2 * 256;
    const int t = threadIdx.x, w = t >> 6, l = t & 63, lo = l & 15, hi = l >> 4;
    const int r3 = l >> 3, c3 = l & 7, sch = c3 ^ r3;
    const int sn = 32 * (w & 1), smg = 32 * (w >> 1);
    const int cg = w & 3, mg = w >> 2;

    const _Float16* hb = h + (size_t)b * CC * NN;
    const _Float16* fTb = fT + (size_t)b * NN * DD;

    // preload query frags + merged stats for this wave's score columns
    f16x8 bq[2][2]; float Mr[2], iSr[2];
    #pragma unroll
    for (int mf = 0; mf < 2; mf++) {
        int m = m0 + smg + 16 * mf + lo;
        #pragma unroll
        for (int kk = 0; kk < 2; kk++)
            bq[mf][kk] = *reinterpret_cast<const f16x8*>(
                gT + ((size_t)b * NN + m) * DD + 32 * kk + 8 * hi);
        float M0 = Mp[(size_t)b * NN + m],       S0 = Sp[(size_t)b * NN + m];
        float M1 = Mp[(size_t)(8 + b) * NN + m], S1 = Sp[(size_t)(8 + b) * NN + m];
        float M = fmaxf(M0, M1);
        float S = S0 * __expf(M0 - M) + S1 * __expf(M1 - M);
        Mr[mf] = M; iSr[mf] = 1.0f / (S + 1e-20f);
    }

    f32x4 o[4][4];
    #pragma unroll
    for (int ci = 0; ci < 4; ci++)
        #pragma unroll
        for (int mi = 0; mi < 4; mi++) o[ci][mi] = (f32x4){0.f, 0.f, 0.f, 0.f};

    #define STAGE(ti, bs) do {                                                         \
        const int _n0 = (ti) * 64;                                                     \
        char* _hd = smem + (bs) * 32768 + (32 * w) * 128;                              \
        const _Float16* _hs = hb + (size_t)(cbase + 32 * w + r3) * NN + _n0 + sch * 8; \
        _Pragma("unroll")                                                              \
        for (int _q = 0; _q < 4; _q++)                                                 \
            gload_lds16((const void*)(_hs + (size_t)(8 * _q) * NN), (void*)(_hd + _q * 1024)); \
        char* _fd = smem + FS0 + (bs) * 8192 + (8 * w) * 128;                          \
        const _Float16* _fs = fTb + (size_t)(_n0 + 8 * w + r3) * DD + sch * 8;         \
        gload_lds16((const void*)_fs, (void*)_fd);                                     \
    } while (0)

    STAGE(0, 0);

    #pragma unroll 1
    for (int i = 0; i < 32; i++) {
        const int cur = i & 1;
        asm volatile("s_waitcnt vmcnt(0)" ::: "memory");
        hard_barrier();                 // stage i ready; prev PV done everywhere
        if (i < 31) STAGE(i + 1, cur ^ 1);

        // ---- scores ----
        char* fsb = smem + FS0 + cur * 8192;
        char* btb = smem + BT0 + cur * 16384;
        f32x4 s4[2][2];
        #pragma unroll
        for (int rf = 0; rf < 2; rf++)
            #pragma unroll
            for (int mf = 0; mf < 2; mf++) s4[rf][mf] = (f32x4){0.f, 0.f, 0.f, 0.f};
        #pragma unroll
        for (int rf = 0; rf < 2; rf++) {
            int nrow = sn + 16 * rf + lo;
            #pragma unroll
            for (int kk = 0; kk < 2; kk++) {
                f16x8 af = *reinterpret_cast<const f16x8*>(
                    fsb + nrow * 128 + (((4 * kk + hi) ^ (lo & 7)) << 4));
                #pragma unroll
                for (int mf = 0; mf < 2; mf++)
                    s4[rf][mf] = __builtin_amdgcn_mfma_f32_16x16x32_f16(af, bq[mf][kk], s4[rf][mf], 0, 0, 0);
            }
        }
        #pragma unroll
        for (int rf = 0; rf < 2; rf++)
            #pragma unroll
            for (int mf = 0; mf < 2; mf++) {
                f16x4 ev;
                #pragma unroll
                for (int j = 0; j < 4; j++)
                    ev[j] = (_Float16)(__expf(s4[rf][mf][j] - Mr[mf]) * iSr[mf]);
                int ml = smg + 16 * mf + lo;
                int nl = sn + 16 * rf + 4 * hi;
                int chunk = (nl >> 3) ^ (lo & 7);
                *reinterpret_cast<f16x4*>(btb + ml * 128 + chunk * 16 + (nl & 7) * 2) = ev;
            }
        asm volatile("s_waitcnt lgkmcnt(0)" ::: "memory");
        hard_barrier();                 // beta ready

        // ---- PV ----
        char* hsb = smem + cur * 32768;
        #pragma unroll
        for (int kk = 0; kk < 2; kk++) {
            f16x8 bb[4];
            #pragma unroll
            for (int mi = 0; mi < 4; mi++) {
                int ml = 64 * mg + 16 * mi + lo;
                bb[mi] = *reinterpret_cast<const f16x8*>(
                    btb + ml * 128 + (((4 * kk + hi) ^ (lo & 7)) << 4));
            }
            #pragma unroll
            for (int ci = 0; ci < 4; ci++) {
                int crow = 64 * cg + 16 * ci + lo;
                f16x8 ah = *reinterpret_cast<const f16x8*>(
                    hsb + crow * 128 + (((4 * kk + hi) ^ (lo & 7)) << 4));
                #pragma unroll
                for (int mi = 0; mi < 4; mi++)
                    o[ci][mi] = __builtin_amdgcn_mfma_f32_16x16x32_f16(ah, bb[mi], o[ci][mi], 0, 0, 0);
            }
        }
    }
    #undef STAGE

    __syncthreads();   // everyone done with tiles; reuse LDS for epilogue

    // ---- epilogue: per-wave LDS transpose + coalesced residual store ----
    float* ob = reinterpret_cast<float*>(smem + w * 9216);   // [64][36] f32, chunk-swizzled
    const float gm = gamma[0];
    const float* xb = x + (size_t)b * CC * NN;
    float* outb = out + (size_t)b * CC * NN;

    #pragma unroll
    for (int half = 0; half < 2; half++) {
        #pragma unroll
        for (int ci = 0; ci < 4; ci++)
            #pragma unroll
            for (int mh = 0; mh < 2; mh++) {
                int mi = 2 * half + mh;
                #pragma unroll
                for (int j = 0; j < 4; j++) {
                    int row = 16 * ci + 4 * hi + j;
                    int ml = 16 * mh + lo;  // 0..31
                    ob[row * 36 + (((ml >> 2) ^ (row & 7)) << 2) + (ml & 3)] = o[ci][mi][j];
                }
            }
        asm volatile("s_waitcnt lgkmcnt(0)" ::: "memory");
        #pragma unroll
        for (int rr = 0; rr < 8; rr++) {
            int row = 8 * rr + r3;
            f32x4 v = *reinterpret_cast<const f32x4*>(ob + row * 36 + ((c3 ^ (row & 7)) << 2));
            size_t idx = (size_t)(cbase + 64 * cg + row) * NN + m0 + 64 * mg + 32 * half + 4 * c3;
            float4 xv = *reinterpret_cast<const float4*>(xb + idx);
            float4 res;
            res.x = gm * v[0] + xv.x; res.y = gm * v[1] + xv.y;
            res.z = gm * v[2] + xv.z; res.w = gm * v[3] + xv.w;
            *reinterpret_cast<float4*>(outb + idx) = res;
        }
        asm volatile("s_waitcnt lgkmcnt(0)" ::: "memory");
    }
}

extern "C" void kernel_launch(void* const* d_in, const int* in_sizes, int n_in,
                              void* d_out, int out_size, void* d_ws, size_t ws_size,
                              hipStream_t stream) {
    (void)in_sizes; (void)n_in; (void)out_size; (void)ws_size;
    const float* x     = (const float*)d_in[0];
    const float* mask  = (const float*)d_in[1];
    const float* Wq    = (const float*)d_in[2];
    const float* Wk    = (const float*)d_in[3];
    const float* Wv    = (const float*)d_in[4];
    const float* gamma = (const float*)d_in[5];
    float* out = (float*)d_out;

    char* ws = (char*)d_ws;
    _Float16* Wf = (_Float16*)(ws + WS_WF);
    _Float16* fT = (_Float16*)(ws + WS_FT);
    _Float16* gT = (_Float16*)(ws + WS_GT);
    _Float16* h  = (_Float16*)(ws + WS_H);
    float* Mp = (float*)(ws + WS_M);
    float* Sp = (float*)(ws + WS_S);

    wconv_kernel<<<160, 256, 0, stream>>>(Wq, Wk, Wv, Wf);
    proj_kernel<<<dim3(32, 8), 512, 0, stream>>>(x, Wf, mask, fT, gT, h);
    stats_kernel<<<512, 512, 0, stream>>>(fT, gT, mask, Mp, Sp);
    hipFuncSetAttribute((const void*)attn2_kernel,
                        hipFuncAttributeMaxDynamicSharedMemorySize, LDS2B);
    attn2_kernel<<<256, 512, LDS2B, stream>>>(fT, gT, h, x, Mp, Sp, gamma, out);
}